// Round 2
// baseline (121.782 us; speedup 1.0000x reference)
//
#include <hip/hip_runtime.h>
#include <math.h>

#define N_MAX 8192
#define N_USERS 1024
#define D 64

// Persistent device scratch (rewritten deterministically every launch).
__device__ int   g_mask_int;            // 1 if mask buffer is int32, 0 if bytes
__device__ int   g_cnt[N_USERS];        // counts, then scatter cursors
__device__ int   g_off[N_USERS + 1];    // exclusive prefix offsets
__device__ int   g_list[N_MAX];         // negative column indices, bucketed by user id
__device__ float g_row[N_MAX];          // per-row loss contribution (0 for unmasked rows)

__device__ __forceinline__ bool mask_at(const void* m, int k, bool as_int) {
    return as_int ? (((const int*)m)[k] != 0)
                  : (((const unsigned char*)m)[k] != 0);
}

// ---------------------------------------------------------------------------
// Kernel 1: detect mask layout, then bucket the negative columns (mask[k]==0)
// by user id. Single block of N_USERS threads.
// ---------------------------------------------------------------------------
__global__ __launch_bounds__(N_USERS) void build_buckets(
    const void* __restrict__ maskp,
    const int* __restrict__ uid, int N)
{
    const int t = threadIdx.x;
    __shared__ int sc[N_USERS];
    __shared__ int s_or;

    // --- mask dtype detection ---------------------------------------------
    // If mask is int32 (values 0/1), every byte at index k%4!=0 (k<N) is 0.
    // If mask is 1-byte bools, ~half of those bytes are 1. Deterministic.
    if (t == 0) s_or = 0;
    __syncthreads();
    {
        const unsigned char* mb = (const unsigned char*)maskp;
        int z = 0;
        for (int k = t; k < N; k += N_USERS)
            if (k & 3) z |= mb[k];
        if (z) atomicOr(&s_or, 1);
    }
    __syncthreads();
    const bool as_int = (s_or == 0);
    if (t == 0) g_mask_int = as_int ? 1 : 0;

    // --- bucket by user id -------------------------------------------------
    g_cnt[t] = 0;
    __syncthreads();

    for (int k = t; k < N; k += N_USERS)
        if (!mask_at(maskp, k, as_int)) atomicAdd(&g_cnt[uid[k]], 1);
    __syncthreads();

    // Hillis-Steele inclusive scan over the 1024 counts.
    const int own = g_cnt[t];
    sc[t] = own;
    __syncthreads();
    for (int off = 1; off < N_USERS; off <<= 1) {
        int v = (t >= off) ? sc[t - off] : 0;
        __syncthreads();
        sc[t] += v;
        __syncthreads();
    }
    const int excl = sc[t] - own;
    g_off[t] = excl;
    if (t == N_USERS - 1) g_off[N_USERS] = sc[t];
    g_cnt[t] = excl;  // reuse as scatter cursor
    __syncthreads();

    for (int k = t; k < N; k += N_USERS)
        if (!mask_at(maskp, k, as_int)) {
            int p = atomicAdd(&g_cnt[uid[k]], 1);
            g_list[p] = k;
        }
}

// ---------------------------------------------------------------------------
// Kernel 2: one wave (64 lanes) per row. Lanes parallelize over candidate
// negative columns; each lane computes a full D=64 dot (input row broadcast
// from LDS, target rows via float4 — target_emb is 2 MB, L2-resident).
// ---------------------------------------------------------------------------
__global__ __launch_bounds__(256) void row_kernel(
    const float* __restrict__ inp, const float* __restrict__ tgt,
    const float* __restrict__ q,   const int* __restrict__ tids,
    const int* __restrict__ uid,   const void* __restrict__ maskp,
    int N)
{
    const int lane = threadIdx.x & 63;
    const int w    = threadIdx.x >> 6;
    const int i    = blockIdx.x * 4 + w;
    __shared__ float in_s[4][D];

    if (i >= N) return;
    const bool as_int = (g_mask_int != 0);
    if (!mask_at(maskp, i, as_int)) { if (lane == 0) g_row[i] = 0.0f; return; }

    // Load my input row; lane d holds element d. Also stage into LDS so every
    // lane can stream the whole row for its own dot products.
    const float a = inp[i * D + lane];
    in_s[w][lane] = a;

    // pos_sim = dot(input_emb[i], target_emb[i]) via butterfly reduce.
    float p = a * tgt[i * D + lane];
    #pragma unroll
    for (int o = 32; o > 0; o >>= 1) p += __shfl_xor(p, o, 64);

    const int u = uid[i];
    int start = g_off[u], end = g_off[u + 1];
    if (end == start) {             // row_has_su == false -> all negatives
        start = 0;
        end = g_off[N_USERS];
    }
    const int my_tid = tids[i];

    float s = 0.0f;
    int   n = 0;
    for (int j = start + lane; j < end; j += 64) {
        const int k = g_list[j];
        if (tids[k] == my_tid) continue;
        const float4* tr = (const float4*)(tgt + k * D);
        const float4* ar = (const float4*)(&in_s[w][0]);
        float dot = 0.0f;
        #pragma unroll
        for (int d4 = 0; d4 < D / 4; ++d4) {
            const float4 t4 = tr[d4];
            const float4 a4 = ar[d4];
            dot += a4.x * t4.x + a4.y * t4.y + a4.z * t4.z + a4.w * t4.w;
        }
        n += 1;
        s += expf(dot) / q[k];
    }
    #pragma unroll
    for (int o = 32; o > 0; o >>= 1) {
        s += __shfl_xor(s, o, 64);
        n += __shfl_xor(n, o, 64);
    }

    if (lane == 0) {
        const float qi      = q[i];
        const float neg_sum = (1.0f - qi) * s / fmaxf((float)n, 1.0f);
        // -pos + log(exp(pos) + neg_sum) == log1p(neg_sum * exp(-pos))
        g_row[i] = log1pf(neg_sum * expf(-p));
    }
}

// ---------------------------------------------------------------------------
// Kernel 3: deterministic fixed-order reduction -> scalar loss.
// ---------------------------------------------------------------------------
__global__ __launch_bounds__(1024) void finalize(
    const void* __restrict__ maskp, float* __restrict__ out, int N)
{
    __shared__ float sf[1024];
    __shared__ int   si[1024];
    const int t = threadIdx.x;
    const bool as_int = (g_mask_int != 0);
    float s = 0.0f;
    int   c = 0;
    for (int idx = t; idx < N; idx += 1024) {
        s += g_row[idx];
        c += mask_at(maskp, idx, as_int) ? 1 : 0;
    }
    sf[t] = s; si[t] = c;
    __syncthreads();
    for (int off = 512; off > 0; off >>= 1) {
        if (t < off) { sf[t] += sf[t + off]; si[t] += si[t + off]; }
        __syncthreads();
    }
    if (t == 0) out[0] = sf[0] / (float)si[0];
}

extern "C" void kernel_launch(void* const* d_in, const int* in_sizes, int n_in,
                              void* d_out, int out_size, void* d_ws, size_t ws_size,
                              hipStream_t stream) {
    const float* inp  = (const float*)d_in[0];
    const float* tgt  = (const float*)d_in[1];
    const float* q    = (const float*)d_in[2];
    const int*   tids = (const int*)d_in[3];
    const int*   uids = (const int*)d_in[4];
    const void*  mask = d_in[5];
    const int N = in_sizes[2];  // q_probas element count

    build_buckets<<<1, N_USERS, 0, stream>>>(mask, uids, N);
    row_kernel<<<(N + 3) / 4, 256, 0, stream>>>(inp, tgt, q, tids, uids, mask, N);
    finalize<<<1, 1024, 0, stream>>>(mask, (float*)d_out, N);
}

// Round 3
// 64.544 us; speedup vs baseline: 1.8868x; 1.8868x over previous
//
#include <hip/hip_runtime.h>
#include <math.h>

#define N_MAX 8192
#define N_USERS 1024
#define D 64
#define REG_BLOCKS 512   // 1024 thr = 16 waves -> 16 rows/block -> 8192 rows
#define FB_BLOCKS  128   // fallback: one 1024-thread block per empty-bucket row

// Persistent device scratch (rewritten deterministically every launch).
__device__ int   g_mask_int;            // 1 if mask buffer is int32, 0 if bytes
__device__ int   g_off[N_USERS + 1];    // exclusive prefix offsets per user
__device__ int   g_list[N_MAX];         // negative column idx, bucketed by user
__device__ int   g_nfb;                 // # fallback rows
__device__ int   g_fb[N_MAX];           // fallback row ids (order-irrelevant)
__device__ float g_row[N_MAX];          // per-row loss (0 for unmasked rows)

__device__ __forceinline__ bool mask_at(const void* m, int k, bool as_int) {
    return as_int ? (((const int*)m)[k] != 0)
                  : (((const unsigned char*)m)[k] != 0);
}

// ---------------------------------------------------------------------------
// Kernel 1: detect mask dtype; bucket negative columns by user id (LDS
// count+scan+scatter); emit list of masked rows with an empty bucket.
// Single block of 1024 threads.
// ---------------------------------------------------------------------------
__global__ __launch_bounds__(N_USERS) void build_buckets(
    const void* __restrict__ maskp,
    const int* __restrict__ uid, int N)
{
    const int t = threadIdx.x;
    __shared__ int cntA[N_USERS];   // per-user negative count (preserved)
    __shared__ int sc[N_USERS];     // scan workspace
    __shared__ int cur[N_USERS];    // scatter cursors
    __shared__ int s_or;

    if (t == 0) { s_or = 0; g_nfb = 0; }
    cntA[t] = 0;
    __syncthreads();

    // --- mask dtype detection: int32 0/1 has zero bytes at k%4!=0 ----------
    {
        const unsigned char* mb = (const unsigned char*)maskp;
        int z = 0;
        for (int k = t; k < N; k += N_USERS)
            if (k & 3) z |= mb[k];
        if (z) atomicOr(&s_or, 1);
    }
    __syncthreads();
    const bool as_int = (s_or == 0);
    if (t == 0) g_mask_int = as_int ? 1 : 0;

    // --- count negatives per user (LDS atomics) ----------------------------
    for (int k = t; k < N; k += N_USERS)
        if (!mask_at(maskp, k, as_int)) atomicAdd(&cntA[uid[k]], 1);
    __syncthreads();

    // --- Hillis-Steele inclusive scan --------------------------------------
    const int own = cntA[t];
    sc[t] = own;
    __syncthreads();
    for (int off = 1; off < N_USERS; off <<= 1) {
        int v = (t >= off) ? sc[t - off] : 0;
        __syncthreads();
        sc[t] += v;
        __syncthreads();
    }
    const int excl = sc[t] - own;
    g_off[t] = excl;
    if (t == N_USERS - 1) g_off[N_USERS] = sc[t];
    cur[t] = excl;
    __syncthreads();

    // --- scatter negatives into buckets ------------------------------------
    for (int k = t; k < N; k += N_USERS)
        if (!mask_at(maskp, k, as_int)) {
            int p = atomicAdd(&cur[uid[k]], 1);
            g_list[p] = k;
        }

    // --- fallback rows: masked && own user's bucket empty ------------------
    for (int i = t; i < N; i += N_USERS)
        if (mask_at(maskp, i, as_int) && cntA[uid[i]] == 0) {
            int p = atomicAdd(&g_nfb, 1);
            g_fb[p] = i;
        }
}

// ---------------------------------------------------------------------------
// Kernel 2 (fused): blocks [0,REG_BLOCKS) -> one wave per row, bucket scan.
// Blocks [REG_BLOCKS, REG_BLOCKS+FB_BLOCKS) -> one 1024-thread block per
// fallback row (grid-stride over g_fb), scanning ALL negatives.
// ---------------------------------------------------------------------------
__global__ __launch_bounds__(1024) void row_kernel(
    const float* __restrict__ inp, const float* __restrict__ tgt,
    const float* __restrict__ q,   const int* __restrict__ tids,
    const int* __restrict__ uid,   const void* __restrict__ maskp,
    int N)
{
    const int t    = threadIdx.x;
    const int lane = t & 63;
    const int w    = t >> 6;
    const int bid  = blockIdx.x;
    const bool as_int = (g_mask_int != 0);

    if (bid < REG_BLOCKS) {
        // ---------------- regular rows: one wave each ----------------------
        __shared__ __align__(16) float in_s[16][D];
        const int i = bid * 16 + w;
        if (i >= N) return;
        if (!mask_at(maskp, i, as_int)) { if (lane == 0) g_row[i] = 0.0f; return; }

        const int u = uid[i];
        const int start = g_off[u], end = g_off[u + 1];
        if (end == start) return;            // fallback block owns this row

        const float a = inp[i * D + lane];
        in_s[w][lane] = a;

        float p = a * tgt[i * D + lane];
        #pragma unroll
        for (int o = 32; o > 0; o >>= 1) p += __shfl_xor(p, o, 64);

        const int my_tid = tids[i];
        float s = 0.0f;
        int   n = 0;
        for (int j = start + lane; j < end; j += 64) {
            const int k = g_list[j];
            if (tids[k] == my_tid) continue;
            const float4* tr = (const float4*)(tgt + k * D);
            const float4* ar = (const float4*)(&in_s[w][0]);
            float dot = 0.0f;
            #pragma unroll
            for (int d4 = 0; d4 < D / 4; ++d4) {
                const float4 t4 = tr[d4];
                const float4 a4 = ar[d4];
                dot += a4.x * t4.x + a4.y * t4.y + a4.z * t4.z + a4.w * t4.w;
            }
            n += 1;
            s += expf(dot) / q[k];
        }
        #pragma unroll
        for (int o = 32; o > 0; o >>= 1) {
            s += __shfl_xor(s, o, 64);
            n += __shfl_xor(n, o, 64);
        }
        if (lane == 0) {
            const float qi      = q[i];
            const float neg_sum = (1.0f - qi) * s / fmaxf((float)n, 1.0f);
            g_row[i] = log1pf(neg_sum * expf(-p));
        }
    } else {
        // ---------------- fallback rows: one block each --------------------
        __shared__ __align__(16) float in_fb[D];
        __shared__ float sfs[16];
        __shared__ int   sfn[16];

        const int nfb  = g_nfb;
        const int ntot = g_off[N_USERS];
        for (int r = bid - REG_BLOCKS; r < nfb; r += FB_BLOCKS) {
            const int i = g_fb[r];
            if (t < D) in_fb[t] = inp[i * D + t];
            __syncthreads();

            float pos = 0.0f;
            if (w == 0) {                    // wave 0 computes pos_sim
                pos = in_fb[lane] * tgt[i * D + lane];
                #pragma unroll
                for (int o = 32; o > 0; o >>= 1) pos += __shfl_xor(pos, o, 64);
            }

            const int my_tid = tids[i];
            float s = 0.0f;
            int   n = 0;
            for (int j = t; j < ntot; j += 1024) {
                const int k = g_list[j];
                if (tids[k] == my_tid) continue;
                const float4* tr = (const float4*)(tgt + k * D);
                const float4* ar = (const float4*)(&in_fb[0]);
                float dot = 0.0f;
                #pragma unroll
                for (int d4 = 0; d4 < D / 4; ++d4) {
                    const float4 t4 = tr[d4];
                    const float4 a4 = ar[d4];
                    dot += a4.x * t4.x + a4.y * t4.y + a4.z * t4.z + a4.w * t4.w;
                }
                n += 1;
                s += expf(dot) / q[k];
            }
            #pragma unroll
            for (int o = 32; o > 0; o >>= 1) {
                s += __shfl_xor(s, o, 64);
                n += __shfl_xor(n, o, 64);
            }
            if (lane == 0) { sfs[w] = s; sfn[w] = n; }
            __syncthreads();
            if (t == 0) {
                float S = 0.0f; int Nn = 0;
                #pragma unroll
                for (int x = 0; x < 16; ++x) { S += sfs[x]; Nn += sfn[x]; }
                const float qi      = q[i];
                const float neg_sum = (1.0f - qi) * S / fmaxf((float)Nn, 1.0f);
                g_row[i] = log1pf(neg_sum * expf(-pos));
            }
            __syncthreads();                 // protect LDS reuse next r
        }
    }
}

// ---------------------------------------------------------------------------
// Kernel 3: deterministic fixed-order reduction -> scalar loss.
// ---------------------------------------------------------------------------
__global__ __launch_bounds__(1024) void finalize(
    const void* __restrict__ maskp, float* __restrict__ out, int N)
{
    __shared__ float sf[1024];
    __shared__ int   si[1024];
    const int t = threadIdx.x;
    const bool as_int = (g_mask_int != 0);
    float s = 0.0f;
    int   c = 0;
    for (int idx = t; idx < N; idx += 1024) {
        s += g_row[idx];
        c += mask_at(maskp, idx, as_int) ? 1 : 0;
    }
    sf[t] = s; si[t] = c;
    __syncthreads();
    for (int off = 512; off > 0; off >>= 1) {
        if (t < off) { sf[t] += sf[t + off]; si[t] += si[t + off]; }
        __syncthreads();
    }
    if (t == 0) out[0] = sf[0] / (float)si[0];
}

extern "C" void kernel_launch(void* const* d_in, const int* in_sizes, int n_in,
                              void* d_out, int out_size, void* d_ws, size_t ws_size,
                              hipStream_t stream) {
    const float* inp  = (const float*)d_in[0];
    const float* tgt  = (const float*)d_in[1];
    const float* q    = (const float*)d_in[2];
    const int*   tids = (const int*)d_in[3];
    const int*   uids = (const int*)d_in[4];
    const void*  mask = d_in[5];
    const int N = in_sizes[2];  // q_probas element count

    build_buckets<<<1, N_USERS, 0, stream>>>(mask, uids, N);
    row_kernel<<<REG_BLOCKS + FB_BLOCKS, 1024, 0, stream>>>(
        inp, tgt, q, tids, uids, mask, N);
    finalize<<<1, 1024, 0, stream>>>(mask, (float*)d_out, N);
}